// Round 17
// baseline (241.291 us; speedup 1.0000x reference)
//
#include <hip/hip_runtime.h>
#include <hip/hip_bf16.h>
#include <math.h>

#define BB 8
#define TT 2048
#define DD 512
#define NSL 32  // slots: 0..15 row-max by tn; 16..31 col-max by tm (tm<p valid)

typedef __attribute__((ext_vector_type(8))) short bf16x8;
typedef __attribute__((ext_vector_type(4))) float f32x4;
typedef __attribute__((ext_vector_type(4))) int i32x4;

__device__ inline float softplus_f(float v) { return log1pf(expf(v)); }

// fast tanh: 1 - 2/(exp2(2*log2e*y)+1); v_exp_f32 + v_rcp_f32, ~1e-6 rel err
__device__ inline float tanh_fast(float y) {
    float e = __builtin_amdgcn_exp2f(y * 2.8853900817779268f);
    return 1.0f - 2.0f * __builtin_amdgcn_rcpf(e + 1.0f);
}
__device__ inline float exp_fast(float y) {
    return __builtin_amdgcn_exp2f(y * 1.4426950408889634f);
}

// f32 -> bf16 via compiler cast (emits v_cvt_pk_bf16_f32 pairs; m240)
__device__ inline unsigned short cvt_bf16(float f) {
    __hip_bfloat16 h = (__hip_bfloat16)f;
    return *reinterpret_cast<unsigned short*>(&h);
}
__device__ inline float bf2f(unsigned short h) {
    unsigned int u = ((unsigned int)h) << 16;
    return __uint_as_float(u);
}

__device__ inline void load_lds16(const void* g, void* l) {
    __builtin_amdgcn_global_load_lds(
        (const __attribute__((address_space(1))) unsigned int*)g,
        (__attribute__((address_space(3))) unsigned int*)l, 16, 0, 0);
}

// ---------------- K1: fused prep + per-row elementwise + reductions ----------------
// 256 threads = 4 waves; one wave per row of D=512; 8 elems/thread.
// inv_std inline; ||ema_out|| per-wave reduce. Block 0 zeroes the 128 panel
// counters used by k2's finisher pass (ws is NOT re-poisoned between replays,
// so the reset must happen every call; k1 completes before k2 starts).
__global__ __launch_bounds__(256) void k1_elem(
    const float* __restrict__ x, const float* __restrict__ ema_mean,
    const float* __restrict__ ema_sq, const float* __restrict__ ema_out,
    const float* __restrict__ p_log_tau, const float* __restrict__ p_lbu,
    const float* __restrict__ p_lbd, const float* __restrict__ p_lg,
    unsigned char* __restrict__ xn8, unsigned short* __restrict__ po,
    int* __restrict__ cnt) {
    if (blockIdx.x == 0 && threadIdx.x < 128) cnt[threadIdx.x] = 0;

    const int row = blockIdx.x * 4 + (threadIdx.x >> 6);
    const int lane = threadIdx.x & 63;
    const size_t base = (size_t)row * DD;
    const int j0 = lane * 4, j1 = 256 + lane * 4;

    // issue all loads first
    float4 xx0 = *reinterpret_cast<const float4*>(x + base + j0);
    float4 xx1 = *reinterpret_cast<const float4*>(x + base + j1);
    float4 mm0 = *reinterpret_cast<const float4*>(ema_mean + j0);
    float4 mm1 = *reinterpret_cast<const float4*>(ema_mean + j1);
    float4 qq0 = *reinterpret_cast<const float4*>(ema_sq + j0);
    float4 qq1 = *reinterpret_cast<const float4*>(ema_sq + j1);
    float4 eo0 = *reinterpret_cast<const float4*>(ema_out + j0);
    float4 eo1 = *reinterpret_cast<const float4*>(ema_out + j1);

    const float tau = expf(p_log_tau[0]);
    const float beta_up = softplus_f(p_lbu[0]);
    const float beta_dn = softplus_f(p_lbd[0]);
    const float gamma = softplus_f(p_lg[0]);

    float xv[8], pg[8];
    float sx2 = 0.f, so2 = 0.f, sod = 0.f, se2 = 0.f;
    float vv[8] = {xx0.x, xx0.y, xx0.z, xx0.w, xx1.x, xx1.y, xx1.z, xx1.w};
    float vm[8] = {mm0.x, mm0.y, mm0.z, mm0.w, mm1.x, mm1.y, mm1.z, mm1.w};
    float vq[8] = {qq0.x, qq0.y, qq0.z, qq0.w, qq1.x, qq1.y, qq1.z, qq1.w};
    float ve[8] = {eo0.x, eo0.y, eo0.z, eo0.w, eo1.x, eo1.y, eo1.z, eo1.w};
#pragma unroll
    for (int e = 0; e < 8; ++e) {
        float xf = vv[e];
        xv[e] = xf;
        float x3 = xf * xf * xf;
        float gl = 0.5f * xf * (1.0f + tanh_fast(0.7978845608028654f * (xf + 0.044715f * x3)));
        float var = fmaxf(vq[e] - vm[e] * vm[e], 1e-4f);
        float istd = __builtin_amdgcn_rcpf(sqrtf(var) + 1e-5f);
        float z = (xf - vm[e]) * istd;
        float th = tanh_fast(gamma * z);
        float up = beta_up * fmaxf(th, 0.0f);
        float dn = beta_dn * fmaxf(-th, 0.0f);
        float gh = fminf(fmaxf(1.0f + up - dn, 0.05f), 8.0f);
        pg[e] = gl * gh;
        sx2 += xf * xf;
        so2 += gl * gl;
        sod += gl * ve[e];
        se2 += ve[e] * ve[e];
    }
#pragma unroll
    for (int off = 32; off; off >>= 1) {
        sx2 += __shfl_xor(sx2, off);
        so2 += __shfl_xor(so2, off);
        sod += __shfl_xor(sod, off);
        se2 += __shfl_xor(se2, off);
    }
    const float qscale = 127.0f * __builtin_amdgcn_rcpf(fmaxf(sqrtf(sx2), 1e-12f));
    const float inv_en = __builtin_amdgcn_rcpf(fmaxf(sqrtf(se2), 1e-12f));
    float cosv = sod * inv_en * __builtin_amdgcn_rcpf(fmaxf(sqrtf(so2), 1e-12f));
    cosv = fminf(fmaxf(cosv, -1.0f), 1.0f);
    const float gcos = exp_fast(-tau * cosv);

#pragma unroll
    for (int c = 0; c < 2; ++c) {
        const int j = c * 256 + lane * 4;
        ushort4 pb;
        pb.x = cvt_bf16(pg[c * 4 + 0] * gcos);
        pb.y = cvt_bf16(pg[c * 4 + 1] * gcos);
        pb.z = cvt_bf16(pg[c * 4 + 2] * gcos);
        pb.w = cvt_bf16(pg[c * 4 + 3] * gcos);
        *reinterpret_cast<ushort4*>(po + base + j) = pb;
        int q0 = __float2int_rn(xv[c * 4 + 0] * qscale);
        int q1 = __float2int_rn(xv[c * 4 + 1] * qscale);
        int q2 = __float2int_rn(xv[c * 4 + 2] * qscale);
        int q3 = __float2int_rn(xv[c * 4 + 3] * qscale);
        int pk = (q0 & 255) | ((q1 & 255) << 8) | ((q2 & 255) << 16) | (q3 << 24);
        *reinterpret_cast<int*>(xn8 + base + j) = pk;
    }
}

// ---------------- K2: sim row/col max + fused gate/scale finisher ----------------
// R14 MFMA core (best measured): 1088 tri-tile blocks, 4 waves, 64x64/wave,
// 3 LDS slots, counted vmcnt(4) boundaries, raw s_barrier. NEW: k3 is folded
// in via dependency counting (rocPRIM lookback pattern): each panel p of batch
// b is touched by exactly 16 tiles (diag once, 15-p row-side, p col-side).
// After writing partial slots: __threadfence (release) + atomicAdd(cnt).
// The block seeing count==15 becomes the panel's FINISHER: acquire fence,
// reduce 32 slots/row, scale PO, write out — overlapped with other blocks'
// MFMA work instead of a separate serial kernel. Output deterministic
// regardless of which block finishes (no dispatch-order assumption, G16-safe;
// device-scope atomics per G12).
__global__ __launch_bounds__(256, 3) void k2_nn(const unsigned char* __restrict__ xn8,
                                                float* __restrict__ partial,
                                                int* __restrict__ cnt,
                                                const unsigned short* __restrict__ po,
                                                float* __restrict__ out,
                                                const float* __restrict__ p_lsn,
                                                const float* __restrict__ p_lwn) {
    __shared__ char lds[49152];  // 3 slots x (A 8 KB | B 8 KB)
    __shared__ int dmn[2];

    const int tid = threadIdx.x;
    const int wave = tid >> 6;
    const int lane = tid & 63;
    const int r15 = lane & 15;
    const int kgrp = lane >> 4;
    const int wr = wave >> 1;  // 0..1 (row half)
    const int wc = wave & 1;   // 0..1 (col half)

    const int bid = blockIdx.x;
    const int b = bid & 7;  // XCD pin (1088 % 8 == 0 -> bijective)
    int t = bid >> 3;       // 0..135
    int tm = 0;
    while (t >= 16 - tm) { t -= 16 - tm; ++tm; }
    const int tn = tm + t;

    const size_t bbase = (size_t)b * TT * DD;
    const unsigned char* Ag = xn8 + bbase + (size_t)tm * 128 * DD;
    const unsigned char* Bg = xn8 + bbase + (size_t)tn * 128 * DD;

    i32x4 acc[4][4];
#pragma unroll
    for (int i = 0; i < 4; ++i)
#pragma unroll
        for (int j = 0; j < 4; ++j) acc[i][j] = (i32x4){0, 0, 0, 0};

    // stage one K-tile (64 i8 cols): A 2 + B 2 loads per thread
    auto stage = [&](int slot, int kt) {
#pragma unroll
        for (int l = 0; l < 2; ++l) {
            const int o = l * 4096 + tid * 16;
            const int sup = o >> 7;
            const int w = (o & 127) ^ ((sup & 7) << 4);
            const int row = sup * 2 + (w >> 6);
            const int cb = w & 63;
            load_lds16(Ag + (size_t)row * DD + kt * 64 + cb, lds + slot * 16384 + o);
            load_lds16(Bg + (size_t)row * DD + kt * 64 + cb, lds + slot * 16384 + 8192 + o);
        }
    };

#define LADDR(R) \
    (((R) >> 1) * 128 + (((((R) & 1) << 6) + (kgrp << 4)) ^ ((((R) >> 1) & 7) << 4)))

    auto compute = [&](int slot) {
        const char* sA = lds + slot * 16384;
        const char* sB = sA + 8192;
        i32x4 av[4], bv[4];
#pragma unroll
        for (int ni = 0; ni < 4; ++ni)
            bv[ni] = *(const i32x4*)(sB + LADDR(wc * 64 + ni * 16 + r15));
#pragma unroll
        for (int mi = 0; mi < 4; ++mi)
            av[mi] = *(const i32x4*)(sA + LADDR(wr * 64 + mi * 16 + r15));
        __builtin_amdgcn_s_setprio(1);
#pragma unroll
        for (int mi = 0; mi < 4; ++mi)
#pragma unroll
            for (int ni = 0; ni < 4; ++ni)
                acc[mi][ni] = __builtin_amdgcn_mfma_i32_16x16x64_i8(av[mi], bv[ni],
                                                                    acc[mi][ni], 0, 0, 0);
        __builtin_amdgcn_s_setprio(0);
    };
#undef LADDR

    // prologue: stage tiles 0,1 (8 loads); vmcnt(4) -> tile 0 landed, tile 1 in flight
    stage(0, 0);
    stage(1, 1);
    asm volatile("s_waitcnt vmcnt(4)" ::: "memory");
    __builtin_amdgcn_s_barrier();
    __builtin_amdgcn_sched_barrier(0);

#pragma unroll
    for (int kt = 0; kt < 8; ++kt) {
        if (kt + 2 < 8) stage((kt + 2) % 3, kt + 2);  // slot of tile kt-1: reads done last iter
        compute(kt % 3);
        if (kt < 7) {
            if (kt + 2 < 8)
                asm volatile("s_waitcnt vmcnt(4)" ::: "memory");  // tile kt+1 landed
            else
                asm volatile("s_waitcnt vmcnt(0)" ::: "memory");  // tail drain
            __builtin_amdgcn_s_barrier();
            __builtin_amdgcn_sched_barrier(0);
        }
    }

    // ---- epilogue: per-tile row/col maxes -> partial ----
    const float inv_qq = 1.0f / (127.0f * 127.0f);
    const bool diag = (tm == tn);
    float accf[4][4][4];
#pragma unroll
    for (int mi = 0; mi < 4; ++mi)
#pragma unroll
        for (int ni = 0; ni < 4; ++ni)
#pragma unroll
            for (int rr = 0; rr < 4; ++rr) {
                float e = (float)acc[mi][ni][rr] * inv_qq;
                if (diag) {
                    const int rl = wr * 64 + mi * 16 + kgrp * 4 + rr;
                    const int cl = wc * 64 + ni * 16 + r15;
                    if (rl == cl) e = -2.0f;
                }
                accf[mi][ni][rr] = e;
            }
    float rmx[4][4];
#pragma unroll
    for (int mi = 0; mi < 4; ++mi)
#pragma unroll
        for (int rr = 0; rr < 4; ++rr) {
            float v = fmaxf(fmaxf(accf[mi][0][rr], accf[mi][1][rr]),
                            fmaxf(accf[mi][2][rr], accf[mi][3][rr]));
            v = fmaxf(v, __shfl_xor(v, 1));
            v = fmaxf(v, __shfl_xor(v, 2));
            v = fmaxf(v, __shfl_xor(v, 4));
            v = fmaxf(v, __shfl_xor(v, 8));
            rmx[mi][rr] = v;
        }
    float cmx[4];
#pragma unroll
    for (int ni = 0; ni < 4; ++ni) {
        float v = -2.0f;
#pragma unroll
        for (int mi = 0; mi < 4; ++mi)
#pragma unroll
            for (int rr = 0; rr < 4; ++rr) v = fmaxf(v, accf[mi][ni][rr]);
        v = fmaxf(v, __shfl_xor(v, 16));
        v = fmaxf(v, __shfl_xor(v, 32));
        cmx[ni] = v;
    }
    __syncthreads();  // all LDS tile reads + stages done; alias reduce bufs
    float* rbuf = (float*)lds;           // [128][2] (wc)
    float* cbuf = (float*)(lds + 1024);  // [128][2] (wr)
    if (r15 == 0) {
#pragma unroll
        for (int mi = 0; mi < 4; ++mi)
#pragma unroll
            for (int rr = 0; rr < 4; ++rr)
                rbuf[(wr * 64 + mi * 16 + kgrp * 4 + rr) * 2 + wc] = rmx[mi][rr];
    }
    if (kgrp == 0) {
#pragma unroll
        for (int ni = 0; ni < 4; ++ni)
            cbuf[(wc * 64 + ni * 16 + r15) * 2 + wr] = cmx[ni];
    }
    __syncthreads();
    if (tid < 128) {
        const float v = fmaxf(rbuf[tid * 2 + 0], rbuf[tid * 2 + 1]);
        partial[((size_t)b * TT + tm * 128 + tid) * NSL + tn] = v;
    } else if (!diag) {
        const int c = tid - 128;
        const float v = fmaxf(cbuf[c * 2 + 0], cbuf[c * 2 + 1]);
        partial[((size_t)b * TT + tn * 128 + c) * NSL + 16 + tm] = v;
    }

    // ---- dependency counting + finisher ----
    __threadfence();   // release: partial writes visible device-wide
    __syncthreads();   // all threads' writes fenced before the atomic
    if (tid == 0) {
        dmn[0] = atomicAdd(&cnt[b * 16 + tm], 1);
        dmn[1] = diag ? -1 : atomicAdd(&cnt[b * 16 + tn], 1);
    }
    __syncthreads();

    auto finish_panel = [&](int pp) {
        __threadfence();  // acquire: other blocks' partial writes
        const float sigma_nn = softplus_f(p_lsn[0]);
        const float w_nn = softplus_f(p_lwn[0]);
        const size_t rowbase = (size_t)b * TT + (size_t)pp * 128;
        for (int r = wave * 32; r < wave * 32 + 32; ++r) {
            const size_t row = rowbase + r;
            float v = -2.0f;
            if (lane < 16) {
                if (lane >= pp) v = partial[row * NSL + lane];
            } else if (lane < NSL) {
                if (lane - 16 < pp) v = partial[row * NSL + lane];
            }
            v = fmaxf(v, __shfl_xor(v, 1));
            v = fmaxf(v, __shfl_xor(v, 2));
            v = fmaxf(v, __shfl_xor(v, 4));
            v = fmaxf(v, __shfl_xor(v, 8));
            v = fmaxf(v, __shfl_xor(v, 16));
            v = fmaxf(v, __shfl_xor(v, 32));
            const float g = 1.0f + w_nn * tanh_fast(sigma_nn * 0.5f * (1.0f - v));
            const size_t base2 = row * DD + lane * 8;
            ushort4 p0 = *reinterpret_cast<const ushort4*>(po + base2);
            ushort4 p1 = *reinterpret_cast<const ushort4*>(po + base2 + 4);
            float4 o0, o1;
            o0.x = bf2f(p0.x) * g; o0.y = bf2f(p0.y) * g;
            o0.z = bf2f(p0.z) * g; o0.w = bf2f(p0.w) * g;
            o1.x = bf2f(p1.x) * g; o1.y = bf2f(p1.y) * g;
            o1.z = bf2f(p1.z) * g; o1.w = bf2f(p1.w) * g;
            *reinterpret_cast<float4*>(out + base2) = o0;
            *reinterpret_cast<float4*>(out + base2 + 4) = o1;
        }
    };

    if (dmn[0] == 15) finish_panel(tm);
    if (dmn[1] == 15) finish_panel(tn);
}

extern "C" void kernel_launch(void* const* d_in, const int* in_sizes, int n_in,
                              void* d_out, int out_size, void* d_ws, size_t ws_size,
                              hipStream_t stream) {
    const float* x = (const float*)d_in[0];
    const float* ema_mean = (const float*)d_in[1];
    const float* ema_sq = (const float*)d_in[2];
    const float* ema_out = (const float*)d_in[3];
    const float* log_tau = (const float*)d_in[4];
    const float* log_beta_up = (const float*)d_in[5];
    const float* log_beta_dn = (const float*)d_in[6];
    const float* log_gamma = (const float*)d_in[7];
    const float* log_sigma_nn = (const float*)d_in[8];
    const float* log_w_nn = (const float*)d_in[9];

    // ws layout: XN8 i8 [B*T*D] (8.39 MB) | PO bf16 [B*T*D] (16.78 MB)
    //            | partial f32[B*T][NSL] (2.1 MB) | cnt i32[128]
    char* ws = (char*)d_ws;
    unsigned char* XN8 = (unsigned char*)ws;
    unsigned short* PO = (unsigned short*)(ws + 8388608);
    float* partial = (float*)(ws + 8388608 + 16777216);
    int* cnt = (int*)(ws + 8388608 + 16777216 + 2097152);
    float* out = (float*)d_out;

    hipLaunchKernelGGL(k1_elem, dim3(BB * TT / 4), dim3(256), 0, stream, x, ema_mean, ema_sq,
                       ema_out, log_tau, log_beta_up, log_beta_dn, log_gamma, XN8, PO, cnt);
    hipLaunchKernelGGL(k2_nn, dim3(BB * 136), dim3(256), 0, stream, XN8, partial, cnt, PO, out,
                       log_sigma_nn, log_w_nn);
}

// Round 18
// 58.522 us; speedup vs baseline: 4.1231x; 4.1231x over previous
//
#include <hip/hip_runtime.h>
#include <hip/hip_bf16.h>
#include <math.h>

#define BB 8
#define TT 2048
#define DD 512
#define NSL 32  // slots: 0..15 row-max by tn; 16..31 col-max by tm (tm<p valid)

typedef __attribute__((ext_vector_type(8))) short bf16x8;
typedef __attribute__((ext_vector_type(4))) float f32x4;
typedef __attribute__((ext_vector_type(4))) int i32x4;

__device__ inline float softplus_f(float v) { return log1pf(expf(v)); }

// fast tanh: 1 - 2/(exp2(2*log2e*y)+1); v_exp_f32 + v_rcp_f32, ~1e-6 rel err
__device__ inline float tanh_fast(float y) {
    float e = __builtin_amdgcn_exp2f(y * 2.8853900817779268f);
    return 1.0f - 2.0f * __builtin_amdgcn_rcpf(e + 1.0f);
}
__device__ inline float exp_fast(float y) {
    return __builtin_amdgcn_exp2f(y * 1.4426950408889634f);
}

// f32 -> bf16 via compiler cast (emits v_cvt_pk_bf16_f32 pairs; m240)
__device__ inline unsigned short cvt_bf16(float f) {
    __hip_bfloat16 h = (__hip_bfloat16)f;
    return *reinterpret_cast<unsigned short*>(&h);
}
__device__ inline float bf2f(unsigned short h) {
    unsigned int u = ((unsigned int)h) << 16;
    return __uint_as_float(u);
}

__device__ inline void load_lds16(const void* g, void* l) {
    __builtin_amdgcn_global_load_lds(
        (const __attribute__((address_space(1))) unsigned int*)g,
        (__attribute__((address_space(3))) unsigned int*)l, 16, 0, 0);
}

// ---------------- K0: per-channel prep (inv_std, normalized ema_out) ----------------
__global__ __launch_bounds__(512) void k0_prep(const float* __restrict__ ema_mean,
                                               const float* __restrict__ ema_sq,
                                               const float* __restrict__ ema_out,
                                               float* __restrict__ inv_std,
                                               float* __restrict__ ema_n) {
    __shared__ float red[8];
    int t = threadIdx.x;  // 512 threads, one per channel
    float m = ema_mean[t];
    float v = ema_sq[t] - m * m;
    v = fmaxf(v, 1e-4f);
    inv_std[t] = 1.0f / (sqrtf(v) + 1e-5f);

    float e = ema_out[t];
    float s = e * e;
#pragma unroll
    for (int off = 32; off; off >>= 1) s += __shfl_xor(s, off);
    if ((t & 63) == 0) red[t >> 6] = s;
    __syncthreads();
    if (t == 0) {
        float tot = 0.f;
        for (int i = 0; i < 8; ++i) tot += red[i];
        red[0] = 1.0f / fmaxf(sqrtf(tot), 1e-12f);
    }
    __syncthreads();
    ema_n[t] = e * red[0];
}

// ---------------- K1: per-row elementwise + reductions ----------------
// 256 threads = 4 waves; one wave per row of D=512; 8 elems/thread.
// VALU-trimmed (exact algebra): gelu = x*rcp(1+exp2(-2log2e*0.79788*t))
// (identity 0.5x(1+tanh y) = x/(1+e^-2y)); z-gate = 1 + beta(sign z)*th
// (identity: 1 + bu*relu(th) - bd*relu(-th) = 1 + select(beta)*th).
__global__ __launch_bounds__(256) void k1_elem(
    const float* __restrict__ x, const float* __restrict__ ema_mean,
    const float* __restrict__ inv_std, const float* __restrict__ ema_n,
    const float* __restrict__ p_log_tau, const float* __restrict__ p_lbu,
    const float* __restrict__ p_lbd, const float* __restrict__ p_lg,
    unsigned char* __restrict__ xn8, unsigned short* __restrict__ po) {
    const int row = blockIdx.x * 4 + (threadIdx.x >> 6);
    const int lane = threadIdx.x & 63;
    const size_t base = (size_t)row * DD;
    const int j0 = lane * 4, j1 = 256 + lane * 4;

    // issue all loads first
    float4 xx0 = *reinterpret_cast<const float4*>(x + base + j0);
    float4 xx1 = *reinterpret_cast<const float4*>(x + base + j1);
    float4 mm0 = *reinterpret_cast<const float4*>(ema_mean + j0);
    float4 mm1 = *reinterpret_cast<const float4*>(ema_mean + j1);
    float4 ii0 = *reinterpret_cast<const float4*>(inv_std + j0);
    float4 ii1 = *reinterpret_cast<const float4*>(inv_std + j1);
    float4 eo0 = *reinterpret_cast<const float4*>(ema_n + j0);
    float4 eo1 = *reinterpret_cast<const float4*>(ema_n + j1);

    const float tau = expf(p_log_tau[0]);
    const float beta_up = softplus_f(p_lbu[0]);
    const float beta_dn = softplus_f(p_lbd[0]);
    const float gamma = softplus_f(p_lg[0]);
    const float g2 = 2.8853900817779268f * gamma;  // 2*log2e*gamma

    float xv[8], pg[8];
    float sx2 = 0.f, so2 = 0.f, sod = 0.f;
    float vv[8] = {xx0.x, xx0.y, xx0.z, xx0.w, xx1.x, xx1.y, xx1.z, xx1.w};
    float vm[8] = {mm0.x, mm0.y, mm0.z, mm0.w, mm1.x, mm1.y, mm1.z, mm1.w};
    float vi[8] = {ii0.x, ii0.y, ii0.z, ii0.w, ii1.x, ii1.y, ii1.z, ii1.w};
    float ve[8] = {eo0.x, eo0.y, eo0.z, eo0.w, eo1.x, eo1.y, eo1.z, eo1.w};
#pragma unroll
    for (int e = 0; e < 8; ++e) {
        float xf = vv[e];
        xv[e] = xf;
        // gelu: x * rcp(1 + exp2(-2*log2e*0.79788*(x + 0.044715 x^3)))
        float x2 = xf * xf;
        float u = x2 * 0.044715f;
        float tt = __builtin_fmaf(u, xf, xf);
        float e1 = __builtin_amdgcn_exp2f(tt * -2.3022082299460352f);
        float gl = xf * __builtin_amdgcn_rcpf(e1 + 1.0f);
        // z-gate: 1 + beta(sign z) * tanh(gamma z)
        float z = (xf - vm[e]) * vi[e];
        float e2 = __builtin_amdgcn_exp2f(z * g2);
        float th = __builtin_fmaf(-2.0f, __builtin_amdgcn_rcpf(e2 + 1.0f), 1.0f);
        float beta = (z > 0.0f) ? beta_up : beta_dn;
        float gh = fminf(fmaxf(__builtin_fmaf(beta, th, 1.0f), 0.05f), 8.0f);
        pg[e] = gl * gh;
        sx2 += x2;
        so2 += gl * gl;
        sod += gl * ve[e];
    }
#pragma unroll
    for (int off = 32; off; off >>= 1) {
        sx2 += __shfl_xor(sx2, off);
        so2 += __shfl_xor(so2, off);
        sod += __shfl_xor(sod, off);
    }
    const float qscale = 127.0f * __builtin_amdgcn_rcpf(fmaxf(sqrtf(sx2), 1e-12f));
    float cosv = sod * __builtin_amdgcn_rcpf(fmaxf(sqrtf(so2), 1e-12f));
    cosv = fminf(fmaxf(cosv, -1.0f), 1.0f);
    const float gcos = exp_fast(-tau * cosv);

#pragma unroll
    for (int c = 0; c < 2; ++c) {
        const int j = c * 256 + lane * 4;
        ushort4 pb;
        pb.x = cvt_bf16(pg[c * 4 + 0] * gcos);
        pb.y = cvt_bf16(pg[c * 4 + 1] * gcos);
        pb.z = cvt_bf16(pg[c * 4 + 2] * gcos);
        pb.w = cvt_bf16(pg[c * 4 + 3] * gcos);
        *reinterpret_cast<ushort4*>(po + base + j) = pb;
        int q0 = __float2int_rn(xv[c * 4 + 0] * qscale);
        int q1 = __float2int_rn(xv[c * 4 + 1] * qscale);
        int q2 = __float2int_rn(xv[c * 4 + 2] * qscale);
        int q3 = __float2int_rn(xv[c * 4 + 3] * qscale);
        int pk = (q0 & 255) | ((q1 & 255) << 8) | ((q2 & 255) << 16) | (q3 << 24);
        *reinterpret_cast<int*>(xn8 + base + j) = pk;
    }
}

// ---------------- K2: symmetric sim row/col max, int8 MFMA, 128x128 tri-tiles ----
// R14 configuration (best measured): 1088 blocks, 4 waves, 64x64/wave + 3 LDS
// slots, counted vmcnt(4) boundaries, raw s_barrier (loads stay in flight
// across barriers, T4). LDS 3 x 16 KB = 48 KB -> 3 blocks/CU (12 waves/CU).
// R8-PMC-verified 0-conflict swizzle; gload_lds dest linear, global source
// inverse-swizzled (rule 21). Epilogue scales 1/127^2.
__global__ __launch_bounds__(256, 3) void k2_nn(const unsigned char* __restrict__ xn8,
                                                float* __restrict__ partial) {
    __shared__ char lds[49152];  // 3 slots x (A 8 KB | B 8 KB)

    const int tid = threadIdx.x;
    const int wave = tid >> 6;
    const int lane = tid & 63;
    const int r15 = lane & 15;
    const int kgrp = lane >> 4;
    const int wr = wave >> 1;  // 0..1 (row half)
    const int wc = wave & 1;   // 0..1 (col half)

    const int bid = blockIdx.x;
    const int b = bid & 7;  // XCD pin (1088 % 8 == 0 -> bijective)
    int t = bid >> 3;       // 0..135
    int tm = 0;
    while (t >= 16 - tm) { t -= 16 - tm; ++tm; }
    const int tn = tm + t;

    const size_t bbase = (size_t)b * TT * DD;
    const unsigned char* Ag = xn8 + bbase + (size_t)tm * 128 * DD;
    const unsigned char* Bg = xn8 + bbase + (size_t)tn * 128 * DD;

    i32x4 acc[4][4];
#pragma unroll
    for (int i = 0; i < 4; ++i)
#pragma unroll
        for (int j = 0; j < 4; ++j) acc[i][j] = (i32x4){0, 0, 0, 0};

    // stage one K-tile (64 i8 cols): A 2 + B 2 loads per thread
    auto stage = [&](int slot, int kt) {
#pragma unroll
        for (int l = 0; l < 2; ++l) {
            const int o = l * 4096 + tid * 16;
            const int sup = o >> 7;
            const int w = (o & 127) ^ ((sup & 7) << 4);
            const int row = sup * 2 + (w >> 6);
            const int cb = w & 63;
            load_lds16(Ag + (size_t)row * DD + kt * 64 + cb, lds + slot * 16384 + o);
            load_lds16(Bg + (size_t)row * DD + kt * 64 + cb, lds + slot * 16384 + 8192 + o);
        }
    };

#define LADDR(R) \
    (((R) >> 1) * 128 + (((((R) & 1) << 6) + (kgrp << 4)) ^ ((((R) >> 1) & 7) << 4)))

    auto compute = [&](int slot) {
        const char* sA = lds + slot * 16384;
        const char* sB = sA + 8192;
        i32x4 av[4], bv[4];
#pragma unroll
        for (int ni = 0; ni < 4; ++ni)
            bv[ni] = *(const i32x4*)(sB + LADDR(wc * 64 + ni * 16 + r15));
#pragma unroll
        for (int mi = 0; mi < 4; ++mi)
            av[mi] = *(const i32x4*)(sA + LADDR(wr * 64 + mi * 16 + r15));
        __builtin_amdgcn_s_setprio(1);
#pragma unroll
        for (int mi = 0; mi < 4; ++mi)
#pragma unroll
            for (int ni = 0; ni < 4; ++ni)
                acc[mi][ni] = __builtin_amdgcn_mfma_i32_16x16x64_i8(av[mi], bv[ni],
                                                                    acc[mi][ni], 0, 0, 0);
        __builtin_amdgcn_s_setprio(0);
    };
#undef LADDR

    // prologue: stage tiles 0,1 (8 loads); vmcnt(4) -> tile 0 landed, tile 1 in flight
    stage(0, 0);
    stage(1, 1);
    asm volatile("s_waitcnt vmcnt(4)" ::: "memory");
    __builtin_amdgcn_s_barrier();
    __builtin_amdgcn_sched_barrier(0);

#pragma unroll
    for (int kt = 0; kt < 8; ++kt) {
        if (kt + 2 < 8) stage((kt + 2) % 3, kt + 2);  // slot of tile kt-1: reads done last iter
        compute(kt % 3);
        if (kt < 7) {
            if (kt + 2 < 8)
                asm volatile("s_waitcnt vmcnt(4)" ::: "memory");  // tile kt+1 landed
            else
                asm volatile("s_waitcnt vmcnt(0)" ::: "memory");  // tail drain
            __builtin_amdgcn_s_barrier();
            __builtin_amdgcn_sched_barrier(0);
        }
    }

    // ---- epilogue ----
    // D layout: col cl = wc*64 + ni*16 + r15, row rl = wr*64 + mi*16 + kgrp*4 + rr
    const float inv_qq = 1.0f / (127.0f * 127.0f);
    const bool diag = (tm == tn);
    float accf[4][4][4];
#pragma unroll
    for (int mi = 0; mi < 4; ++mi)
#pragma unroll
        for (int ni = 0; ni < 4; ++ni)
#pragma unroll
            for (int rr = 0; rr < 4; ++rr) {
                float e = (float)acc[mi][ni][rr] * inv_qq;
                if (diag) {
                    const int rl = wr * 64 + mi * 16 + kgrp * 4 + rr;
                    const int cl = wc * 64 + ni * 16 + r15;
                    if (rl == cl) e = -2.0f;
                }
                accf[mi][ni][rr] = e;
            }
    // row-max: fold ni, shfl over the 16 col-lanes
    float rmx[4][4];
#pragma unroll
    for (int mi = 0; mi < 4; ++mi)
#pragma unroll
        for (int rr = 0; rr < 4; ++rr) {
            float v = fmaxf(fmaxf(accf[mi][0][rr], accf[mi][1][rr]),
                            fmaxf(accf[mi][2][rr], accf[mi][3][rr]));
            v = fmaxf(v, __shfl_xor(v, 1));
            v = fmaxf(v, __shfl_xor(v, 2));
            v = fmaxf(v, __shfl_xor(v, 4));
            v = fmaxf(v, __shfl_xor(v, 8));
            rmx[mi][rr] = v;
        }
    // col-max: fold mi,rr in-lane, shfl across kgrp
    float cmx[4];
#pragma unroll
    for (int ni = 0; ni < 4; ++ni) {
        float v = -2.0f;
#pragma unroll
        for (int mi = 0; mi < 4; ++mi)
#pragma unroll
            for (int rr = 0; rr < 4; ++rr) v = fmaxf(v, accf[mi][ni][rr]);
        v = fmaxf(v, __shfl_xor(v, 16));
        v = fmaxf(v, __shfl_xor(v, 32));
        cmx[ni] = v;
    }
    __syncthreads();  // all LDS tile reads + stages done; alias reduce bufs
    float* rbuf = (float*)lds;           // [128][2] (wc)
    float* cbuf = (float*)(lds + 1024);  // [128][2] (wr)
    if (r15 == 0) {
#pragma unroll
        for (int mi = 0; mi < 4; ++mi)
#pragma unroll
            for (int rr = 0; rr < 4; ++rr)
                rbuf[(wr * 64 + mi * 16 + kgrp * 4 + rr) * 2 + wc] = rmx[mi][rr];
    }
    if (kgrp == 0) {
#pragma unroll
        for (int ni = 0; ni < 4; ++ni)
            cbuf[(wc * 64 + ni * 16 + r15) * 2 + wr] = cmx[ni];
    }
    __syncthreads();
    if (tid < 128) {
        const float v = fmaxf(rbuf[tid * 2 + 0], rbuf[tid * 2 + 1]);
        partial[((size_t)b * TT + tm * 128 + tid) * NSL + tn] = v;
    } else if (!diag) {
        const int c = tid - 128;
        const float v = fmaxf(cbuf[c * 2 + 0], cbuf[c * 2 + 1]);
        partial[((size_t)b * TT + tn * 128 + c) * NSL + 16 + tm] = v;
    }
}

// ---------------- K3: reduce partial maxes + gate_nn scale + final write ----------------
// 256 threads = 4 waves; one wave per row; reads bf16 PO, writes f32 out.
// Row in 128-panel p: valid slots = {tn : tn >= p} U {16+tm : tm < p}.
__global__ __launch_bounds__(256) void k3_scale(float* __restrict__ out,
                                                const unsigned short* __restrict__ po,
                                                const float* __restrict__ partial,
                                                const float* __restrict__ p_lsn,
                                                const float* __restrict__ p_lwn) {
    const int row = blockIdx.x * 4 + (threadIdx.x >> 6);
    const int lane = threadIdx.x & 63;
    const float sigma_nn = softplus_f(p_lsn[0]);
    const float w_nn = softplus_f(p_lwn[0]);

    const int p = (row & (TT - 1)) >> 7;  // 128-row panel of this row
    float v = -2.0f;
    if (lane < 16) {
        if (lane >= p) v = partial[(size_t)row * NSL + lane];
    } else if (lane < NSL) {
        if (lane - 16 < p) v = partial[(size_t)row * NSL + lane];
    }
    v = fmaxf(v, __shfl_xor(v, 1));
    v = fmaxf(v, __shfl_xor(v, 2));
    v = fmaxf(v, __shfl_xor(v, 4));
    v = fmaxf(v, __shfl_xor(v, 8));
    v = fmaxf(v, __shfl_xor(v, 16));
    v = fmaxf(v, __shfl_xor(v, 32));
    const float g = 1.0f + w_nn * tanh_fast(sigma_nn * 0.5f * (1.0f - v));

    const size_t base = (size_t)row * DD + lane * 8;
    ushort4 p0 = *reinterpret_cast<const ushort4*>(po + base);
    ushort4 p1 = *reinterpret_cast<const ushort4*>(po + base + 4);
    float4 o0, o1;
    o0.x = bf2f(p0.x) * g; o0.y = bf2f(p0.y) * g;
    o0.z = bf2f(p0.z) * g; o0.w = bf2f(p0.w) * g;
    o1.x = bf2f(p1.x) * g; o1.y = bf2f(p1.y) * g;
    o1.z = bf2f(p1.z) * g; o1.w = bf2f(p1.w) * g;
    *reinterpret_cast<float4*>(out + base) = o0;
    *reinterpret_cast<float4*>(out + base + 4) = o1;
}

extern "C" void kernel_launch(void* const* d_in, const int* in_sizes, int n_in,
                              void* d_out, int out_size, void* d_ws, size_t ws_size,
                              hipStream_t stream) {
    const float* x = (const float*)d_in[0];
    const float* ema_mean = (const float*)d_in[1];
    const float* ema_sq = (const float*)d_in[2];
    const float* ema_out = (const float*)d_in[3];
    const float* log_tau = (const float*)d_in[4];
    const float* log_beta_up = (const float*)d_in[5];
    const float* log_beta_dn = (const float*)d_in[6];
    const float* log_gamma = (const float*)d_in[7];
    const float* log_sigma_nn = (const float*)d_in[8];
    const float* log_w_nn = (const float*)d_in[9];

    // ws layout: XN8 i8 [B*T*D] (8.39 MB) | PO bf16 [B*T*D] (16.78 MB)
    //            | partial f32[B*T][NSL] (2.1 MB) | inv_std f32[512] | ema_n f32[512]
    char* ws = (char*)d_ws;
    unsigned char* XN8 = (unsigned char*)ws;
    unsigned short* PO = (unsigned short*)(ws + 8388608);
    float* partial = (float*)(ws + 8388608 + 16777216);
    float* inv_std = (float*)(ws + 8388608 + 16777216 + 2097152);
    float* ema_n = (float*)(ws + 8388608 + 16777216 + 2097152 + 2048);
    float* out = (float*)d_out;

    hipLaunchKernelGGL(k0_prep, dim3(1), dim3(512), 0, stream, ema_mean, ema_sq, ema_out,
                       inv_std, ema_n);
    hipLaunchKernelGGL(k1_elem, dim3(BB * TT / 4), dim3(256), 0, stream, x, ema_mean, inv_std,
                       ema_n, log_tau, log_beta_up, log_beta_dn, log_gamma, XN8, PO);
    hipLaunchKernelGGL(k2_nn, dim3(BB * 136), dim3(256), 0, stream, XN8, partial);
    hipLaunchKernelGGL(k3_scale, dim3(BB * TT / 4), dim3(256), 0, stream, out, PO, partial,
                       log_sigma_nn, log_w_nn);
}

// Round 19
// 57.916 us; speedup vs baseline: 4.1662x; 1.0105x over previous
//
#include <hip/hip_runtime.h>
#include <hip/hip_bf16.h>
#include <math.h>

#define BB 8
#define TT 2048
#define DD 512
#define NSL 32  // slots: 0..15 row-max by tn; 16..31 col-max by tm (tm<p valid)

typedef __attribute__((ext_vector_type(8))) short bf16x8;
typedef __attribute__((ext_vector_type(4))) float f32x4;
typedef __attribute__((ext_vector_type(4))) int i32x4;

__device__ inline float softplus_f(float v) { return log1pf(expf(v)); }

// fast tanh: 1 - 2/(exp2(2*log2e*y)+1); v_exp_f32 + v_rcp_f32, ~1e-6 rel err
__device__ inline float tanh_fast(float y) {
    float e = __builtin_amdgcn_exp2f(y * 2.8853900817779268f);
    return 1.0f - 2.0f * __builtin_amdgcn_rcpf(e + 1.0f);
}
__device__ inline float exp_fast(float y) {
    return __builtin_amdgcn_exp2f(y * 1.4426950408889634f);
}

// f32 -> bf16 via compiler cast (emits v_cvt_pk_bf16_f32 pairs; m240)
__device__ inline unsigned short cvt_bf16(float f) {
    __hip_bfloat16 h = (__hip_bfloat16)f;
    return *reinterpret_cast<unsigned short*>(&h);
}
__device__ inline float bf2f(unsigned short h) {
    unsigned int u = ((unsigned int)h) << 16;
    return __uint_as_float(u);
}

__device__ inline void load_lds16(const void* g, void* l) {
    __builtin_amdgcn_global_load_lds(
        (const __attribute__((address_space(1))) unsigned int*)g,
        (__attribute__((address_space(3))) unsigned int*)l, 16, 0, 0);
}

// ---------------- K1: fused prep + per-row elementwise + reductions ----------------
// 256 threads = 4 waves; one wave per row of D=512; 8 elems/thread.
// inv_std inline (R13-proven free: overlaps memory latency); ||ema_out||
// per-wave reduce. R18 algebra: gelu = x*rcp(1+exp2(-2log2e*0.79788*t));
// z-gate = 1 + beta(sign(x-m))*tanh(gamma z) with istd*g2 folded into one mul.
__global__ __launch_bounds__(256) void k1_elem(
    const float* __restrict__ x, const float* __restrict__ ema_mean,
    const float* __restrict__ ema_sq, const float* __restrict__ ema_out,
    const float* __restrict__ p_log_tau, const float* __restrict__ p_lbu,
    const float* __restrict__ p_lbd, const float* __restrict__ p_lg,
    unsigned char* __restrict__ xn8, unsigned short* __restrict__ po) {
    const int row = blockIdx.x * 4 + (threadIdx.x >> 6);
    const int lane = threadIdx.x & 63;
    const size_t base = (size_t)row * DD;
    const int j0 = lane * 4, j1 = 256 + lane * 4;

    // issue all loads first
    float4 xx0 = *reinterpret_cast<const float4*>(x + base + j0);
    float4 xx1 = *reinterpret_cast<const float4*>(x + base + j1);
    float4 mm0 = *reinterpret_cast<const float4*>(ema_mean + j0);
    float4 mm1 = *reinterpret_cast<const float4*>(ema_mean + j1);
    float4 qq0 = *reinterpret_cast<const float4*>(ema_sq + j0);
    float4 qq1 = *reinterpret_cast<const float4*>(ema_sq + j1);
    float4 eo0 = *reinterpret_cast<const float4*>(ema_out + j0);
    float4 eo1 = *reinterpret_cast<const float4*>(ema_out + j1);

    const float tau = expf(p_log_tau[0]);
    const float beta_up = softplus_f(p_lbu[0]);
    const float beta_dn = softplus_f(p_lbd[0]);
    const float gamma = softplus_f(p_lg[0]);
    const float g2 = 2.8853900817779268f * gamma;  // 2*log2e*gamma

    float xv[8], pg[8];
    float sx2 = 0.f, so2 = 0.f, sod = 0.f, se2 = 0.f;
    float vv[8] = {xx0.x, xx0.y, xx0.z, xx0.w, xx1.x, xx1.y, xx1.z, xx1.w};
    float vm[8] = {mm0.x, mm0.y, mm0.z, mm0.w, mm1.x, mm1.y, mm1.z, mm1.w};
    float vq[8] = {qq0.x, qq0.y, qq0.z, qq0.w, qq1.x, qq1.y, qq1.z, qq1.w};
    float ve[8] = {eo0.x, eo0.y, eo0.z, eo0.w, eo1.x, eo1.y, eo1.z, eo1.w};
#pragma unroll
    for (int e = 0; e < 8; ++e) {
        float xf = vv[e];
        xv[e] = xf;
        // gelu: x * rcp(1 + exp2(-2*log2e*0.79788*(x + 0.044715 x^3)))
        float x2 = xf * xf;
        float u = x2 * 0.044715f;
        float tt = __builtin_fmaf(u, xf, xf);
        float e1 = __builtin_amdgcn_exp2f(tt * -2.3022082299460352f);
        float gl = xf * __builtin_amdgcn_rcpf(e1 + 1.0f);
        // z-gate: 1 + beta(sign(x-m)) * tanh(gamma*(x-m)*istd), istd*g2 folded
        float var = fmaxf(vq[e] - vm[e] * vm[e], 1e-4f);
        float istd = __builtin_amdgcn_rcpf(sqrtf(var) + 1e-5f);
        float dm = xf - vm[e];
        float e2 = __builtin_amdgcn_exp2f(dm * (istd * g2));
        float th = __builtin_fmaf(-2.0f, __builtin_amdgcn_rcpf(e2 + 1.0f), 1.0f);
        float beta = (dm > 0.0f) ? beta_up : beta_dn;
        float gh = fminf(fmaxf(__builtin_fmaf(beta, th, 1.0f), 0.05f), 8.0f);
        pg[e] = gl * gh;
        sx2 += x2;
        so2 += gl * gl;
        sod += gl * ve[e];
        se2 += ve[e] * ve[e];
    }
#pragma unroll
    for (int off = 32; off; off >>= 1) {
        sx2 += __shfl_xor(sx2, off);
        so2 += __shfl_xor(so2, off);
        sod += __shfl_xor(sod, off);
        se2 += __shfl_xor(se2, off);
    }
    const float qscale = 127.0f * __builtin_amdgcn_rcpf(fmaxf(sqrtf(sx2), 1e-12f));
    const float inv_en = __builtin_amdgcn_rcpf(fmaxf(sqrtf(se2), 1e-12f));
    float cosv = sod * inv_en * __builtin_amdgcn_rcpf(fmaxf(sqrtf(so2), 1e-12f));
    cosv = fminf(fmaxf(cosv, -1.0f), 1.0f);
    const float gcos = exp_fast(-tau * cosv);

#pragma unroll
    for (int c = 0; c < 2; ++c) {
        const int j = c * 256 + lane * 4;
        ushort4 pb;
        pb.x = cvt_bf16(pg[c * 4 + 0] * gcos);
        pb.y = cvt_bf16(pg[c * 4 + 1] * gcos);
        pb.z = cvt_bf16(pg[c * 4 + 2] * gcos);
        pb.w = cvt_bf16(pg[c * 4 + 3] * gcos);
        *reinterpret_cast<ushort4*>(po + base + j) = pb;
        int q0 = __float2int_rn(xv[c * 4 + 0] * qscale);
        int q1 = __float2int_rn(xv[c * 4 + 1] * qscale);
        int q2 = __float2int_rn(xv[c * 4 + 2] * qscale);
        int q3 = __float2int_rn(xv[c * 4 + 3] * qscale);
        int pk = (q0 & 255) | ((q1 & 255) << 8) | ((q2 & 255) << 16) | (q3 << 24);
        *reinterpret_cast<int*>(xn8 + base + j) = pk;
    }
}

// ---------------- K2: symmetric sim row/col max, int8 MFMA, 128x128 tri-tiles ----
// R14 configuration (best measured): 1088 blocks, 4 waves, 64x64/wave + 3 LDS
// slots, counted vmcnt(4) boundaries, raw s_barrier (loads stay in flight
// across barriers, T4). LDS 3 x 16 KB = 48 KB -> 3 blocks/CU (12 waves/CU).
// R8-PMC-verified 0-conflict swizzle; gload_lds dest linear, global source
// inverse-swizzled (rule 21). Epilogue scales 1/127^2.
__global__ __launch_bounds__(256, 3) void k2_nn(const unsigned char* __restrict__ xn8,
                                                float* __restrict__ partial) {
    __shared__ char lds[49152];  // 3 slots x (A 8 KB | B 8 KB)

    const int tid = threadIdx.x;
    const int wave = tid >> 6;
    const int lane = tid & 63;
    const int r15 = lane & 15;
    const int kgrp = lane >> 4;
    const int wr = wave >> 1;  // 0..1 (row half)
    const int wc = wave & 1;   // 0..1 (col half)

    const int bid = blockIdx.x;
    const int b = bid & 7;  // XCD pin (1088 % 8 == 0 -> bijective)
    int t = bid >> 3;       // 0..135
    int tm = 0;
    while (t >= 16 - tm) { t -= 16 - tm; ++tm; }
    const int tn = tm + t;

    const size_t bbase = (size_t)b * TT * DD;
    const unsigned char* Ag = xn8 + bbase + (size_t)tm * 128 * DD;
    const unsigned char* Bg = xn8 + bbase + (size_t)tn * 128 * DD;

    i32x4 acc[4][4];
#pragma unroll
    for (int i = 0; i < 4; ++i)
#pragma unroll
        for (int j = 0; j < 4; ++j) acc[i][j] = (i32x4){0, 0, 0, 0};

    // stage one K-tile (64 i8 cols): A 2 + B 2 loads per thread
    auto stage = [&](int slot, int kt) {
#pragma unroll
        for (int l = 0; l < 2; ++l) {
            const int o = l * 4096 + tid * 16;
            const int sup = o >> 7;
            const int w = (o & 127) ^ ((sup & 7) << 4);
            const int row = sup * 2 + (w >> 6);
            const int cb = w & 63;
            load_lds16(Ag + (size_t)row * DD + kt * 64 + cb, lds + slot * 16384 + o);
            load_lds16(Bg + (size_t)row * DD + kt * 64 + cb, lds + slot * 16384 + 8192 + o);
        }
    };

#define LADDR(R) \
    (((R) >> 1) * 128 + (((((R) & 1) << 6) + (kgrp << 4)) ^ ((((R) >> 1) & 7) << 4)))

    auto compute = [&](int slot) {
        const char* sA = lds + slot * 16384;
        const char* sB = sA + 8192;
        i32x4 av[4], bv[4];
#pragma unroll
        for (int ni = 0; ni < 4; ++ni)
            bv[ni] = *(const i32x4*)(sB + LADDR(wc * 64 + ni * 16 + r15));
#pragma unroll
        for (int mi = 0; mi < 4; ++mi)
            av[mi] = *(const i32x4*)(sA + LADDR(wr * 64 + mi * 16 + r15));
        __builtin_amdgcn_s_setprio(1);
#pragma unroll
        for (int mi = 0; mi < 4; ++mi)
#pragma unroll
            for (int ni = 0; ni < 4; ++ni)
                acc[mi][ni] = __builtin_amdgcn_mfma_i32_16x16x64_i8(av[mi], bv[ni],
                                                                    acc[mi][ni], 0, 0, 0);
        __builtin_amdgcn_s_setprio(0);
    };
#undef LADDR

    // prologue: stage tiles 0,1 (8 loads); vmcnt(4) -> tile 0 landed, tile 1 in flight
    stage(0, 0);
    stage(1, 1);
    asm volatile("s_waitcnt vmcnt(4)" ::: "memory");
    __builtin_amdgcn_s_barrier();
    __builtin_amdgcn_sched_barrier(0);

#pragma unroll
    for (int kt = 0; kt < 8; ++kt) {
        if (kt + 2 < 8) stage((kt + 2) % 3, kt + 2);  // slot of tile kt-1: reads done last iter
        compute(kt % 3);
        if (kt < 7) {
            if (kt + 2 < 8)
                asm volatile("s_waitcnt vmcnt(4)" ::: "memory");  // tile kt+1 landed
            else
                asm volatile("s_waitcnt vmcnt(0)" ::: "memory");  // tail drain
            __builtin_amdgcn_s_barrier();
            __builtin_amdgcn_sched_barrier(0);
        }
    }

    // ---- epilogue ----
    // D layout: col cl = wc*64 + ni*16 + r15, row rl = wr*64 + mi*16 + kgrp*4 + rr
    const float inv_qq = 1.0f / (127.0f * 127.0f);
    const bool diag = (tm == tn);
    float accf[4][4][4];
#pragma unroll
    for (int mi = 0; mi < 4; ++mi)
#pragma unroll
        for (int ni = 0; ni < 4; ++ni)
#pragma unroll
            for (int rr = 0; rr < 4; ++rr) {
                float e = (float)acc[mi][ni][rr] * inv_qq;
                if (diag) {
                    const int rl = wr * 64 + mi * 16 + kgrp * 4 + rr;
                    const int cl = wc * 64 + ni * 16 + r15;
                    if (rl == cl) e = -2.0f;
                }
                accf[mi][ni][rr] = e;
            }
    // row-max: fold ni, shfl over the 16 col-lanes
    float rmx[4][4];
#pragma unroll
    for (int mi = 0; mi < 4; ++mi)
#pragma unroll
        for (int rr = 0; rr < 4; ++rr) {
            float v = fmaxf(fmaxf(accf[mi][0][rr], accf[mi][1][rr]),
                            fmaxf(accf[mi][2][rr], accf[mi][3][rr]));
            v = fmaxf(v, __shfl_xor(v, 1));
            v = fmaxf(v, __shfl_xor(v, 2));
            v = fmaxf(v, __shfl_xor(v, 4));
            v = fmaxf(v, __shfl_xor(v, 8));
            rmx[mi][rr] = v;
        }
    // col-max: fold mi,rr in-lane, shfl across kgrp
    float cmx[4];
#pragma unroll
    for (int ni = 0; ni < 4; ++ni) {
        float v = -2.0f;
#pragma unroll
        for (int mi = 0; mi < 4; ++mi)
#pragma unroll
            for (int rr = 0; rr < 4; ++rr) v = fmaxf(v, accf[mi][ni][rr]);
        v = fmaxf(v, __shfl_xor(v, 16));
        v = fmaxf(v, __shfl_xor(v, 32));
        cmx[ni] = v;
    }
    __syncthreads();  // all LDS tile reads + stages done; alias reduce bufs
    float* rbuf = (float*)lds;           // [128][2] (wc)
    float* cbuf = (float*)(lds + 1024);  // [128][2] (wr)
    if (r15 == 0) {
#pragma unroll
        for (int mi = 0; mi < 4; ++mi)
#pragma unroll
            for (int rr = 0; rr < 4; ++rr)
                rbuf[(wr * 64 + mi * 16 + kgrp * 4 + rr) * 2 + wc] = rmx[mi][rr];
    }
    if (kgrp == 0) {
#pragma unroll
        for (int ni = 0; ni < 4; ++ni)
            cbuf[(wc * 64 + ni * 16 + r15) * 2 + wr] = cmx[ni];
    }
    __syncthreads();
    if (tid < 128) {
        const float v = fmaxf(rbuf[tid * 2 + 0], rbuf[tid * 2 + 1]);
        partial[((size_t)b * TT + tm * 128 + tid) * NSL + tn] = v;
    } else if (!diag) {
        const int c = tid - 128;
        const float v = fmaxf(cbuf[c * 2 + 0], cbuf[c * 2 + 1]);
        partial[((size_t)b * TT + tn * 128 + c) * NSL + 16 + tm] = v;
    }
}

// ---------------- K3: reduce partial maxes + gate_nn scale + final write ----------------
// 256 threads = 4 waves; one wave per row; reads bf16 PO, writes f32 out.
// Row in 128-panel p: valid slots = {tn : tn >= p} U {16+tm : tm < p}.
__global__ __launch_bounds__(256) void k3_scale(float* __restrict__ out,
                                                const unsigned short* __restrict__ po,
                                                const float* __restrict__ partial,
                                                const float* __restrict__ p_lsn,
                                                const float* __restrict__ p_lwn) {
    const int row = blockIdx.x * 4 + (threadIdx.x >> 6);
    const int lane = threadIdx.x & 63;
    const float sigma_nn = softplus_f(p_lsn[0]);
    const float w_nn = softplus_f(p_lwn[0]);

    const int p = (row & (TT - 1)) >> 7;  // 128-row panel of this row
    float v = -2.0f;
    if (lane < 16) {
        if (lane >= p) v = partial[(size_t)row * NSL + lane];
    } else if (lane < NSL) {
        if (lane - 16 < p) v = partial[(size_t)row * NSL + lane];
    }
    v = fmaxf(v, __shfl_xor(v, 1));
    v = fmaxf(v, __shfl_xor(v, 2));
    v = fmaxf(v, __shfl_xor(v, 4));
    v = fmaxf(v, __shfl_xor(v, 8));
    v = fmaxf(v, __shfl_xor(v, 16));
    v = fmaxf(v, __shfl_xor(v, 32));
    const float g = 1.0f + w_nn * tanh_fast(sigma_nn * 0.5f * (1.0f - v));

    const size_t base = (size_t)row * DD + lane * 8;
    ushort4 p0 = *reinterpret_cast<const ushort4*>(po + base);
    ushort4 p1 = *reinterpret_cast<const ushort4*>(po + base + 4);
    float4 o0, o1;
    o0.x = bf2f(p0.x) * g; o0.y = bf2f(p0.y) * g;
    o0.z = bf2f(p0.z) * g; o0.w = bf2f(p0.w) * g;
    o1.x = bf2f(p1.x) * g; o1.y = bf2f(p1.y) * g;
    o1.z = bf2f(p1.z) * g; o1.w = bf2f(p1.w) * g;
    *reinterpret_cast<float4*>(out + base) = o0;
    *reinterpret_cast<float4*>(out + base + 4) = o1;
}

extern "C" void kernel_launch(void* const* d_in, const int* in_sizes, int n_in,
                              void* d_out, int out_size, void* d_ws, size_t ws_size,
                              hipStream_t stream) {
    const float* x = (const float*)d_in[0];
    const float* ema_mean = (const float*)d_in[1];
    const float* ema_sq = (const float*)d_in[2];
    const float* ema_out = (const float*)d_in[3];
    const float* log_tau = (const float*)d_in[4];
    const float* log_beta_up = (const float*)d_in[5];
    const float* log_beta_dn = (const float*)d_in[6];
    const float* log_gamma = (const float*)d_in[7];
    const float* log_sigma_nn = (const float*)d_in[8];
    const float* log_w_nn = (const float*)d_in[9];

    // ws layout: XN8 i8 [B*T*D] (8.39 MB) | PO bf16 [B*T*D] (16.78 MB)
    //            | partial f32[B*T][NSL] (2.1 MB)
    char* ws = (char*)d_ws;
    unsigned char* XN8 = (unsigned char*)ws;
    unsigned short* PO = (unsigned short*)(ws + 8388608);
    float* partial = (float*)(ws + 8388608 + 16777216);
    float* out = (float*)d_out;

    hipLaunchKernelGGL(k1_elem, dim3(BB * TT / 4), dim3(256), 0, stream, x, ema_mean, ema_sq,
                       ema_out, log_tau, log_beta_up, log_beta_dn, log_gamma, XN8, PO);
    hipLaunchKernelGGL(k2_nn, dim3(BB * 136), dim3(256), 0, stream, XN8, partial);
    hipLaunchKernelGGL(k3_scale, dim3(BB * TT / 4), dim3(256), 0, stream, out, PO, partial,
                       log_sigma_nn, log_w_nn);
}